// Round 4
// baseline (4673.506 us; speedup 1.0000x reference)
//
#include <hip/hip_runtime.h>

#define L 128
#define SW 9
#define NB 4

// ---------------------------------------------------------------------------
// conv0: input image is x[n,row,c] broadcast along strip width (both passes).
// Pass A (p=0): channels [0,768) of w0, real biases.
// Pass B (p=1): channels [768,1536) of w0, spatially transposed (dj,di), no bias.
// Output: bufA[pn][i][s][768]
// ---------------------------------------------------------------------------
__global__ __launch_bounds__(256) void conv0_kernel(
    const float* __restrict__ batch, const float* __restrict__ w0,
    const float* __restrict__ b0, float* __restrict__ out)
{
  const int t  = threadIdx.x;
  const int i0 = blockIdx.x * 2;
  const int pn = blockIdx.y;
  const int p  = pn >> 2, n = pn & 3;

  float acc[2][SW][3];
#pragma unroll
  for (int ii = 0; ii < 2; ++ii)
#pragma unroll
    for (int s = 0; s < SW; ++s)
#pragma unroll
      for (int cc = 0; cc < 3; ++cc)
        acc[ii][s][cc] = p ? 0.f : b0[t + 256 * cc];

  for (int c = 0; c < 768; ++c) {
    float xv[4];
#pragma unroll
    for (int r = 0; r < 4; ++r) {
      int row = i0 - 1 + r;
      xv[r] = (row >= 0 && row < L) ? batch[(row * NB + n) * 768 + c] : 0.f;
    }
#pragma unroll
    for (int di = 0; di < 3; ++di) {
#pragma unroll
      for (int cc = 0; cc < 3; ++cc) {
        const int co = t + 256 * cc;
        float w3[3];
#pragma unroll
        for (int dj = 0; dj < 3; ++dj) {
          const int a = p ? (dj * 3 + di) : (di * 3 + dj);
          w3[dj] = w0[(a * 1536 + p * 768 + c) * 768 + co];
        }
        const float wfull = w3[0] + w3[1] + w3[2];
        const float wl = w3[1] + w3[2];   // s = 0 (left border: dj=-1 invalid)
        const float wr = w3[0] + w3[1];   // s = 8 (right border: dj=+1 invalid)
#pragma unroll
        for (int ii = 0; ii < 2; ++ii) {
          const float xr = xv[ii + di];
          acc[ii][0][cc] += xr * wl;
          acc[ii][8][cc] += xr * wr;
#pragma unroll
          for (int s = 1; s < 8; ++s) acc[ii][s][cc] += xr * wfull;
        }
      }
    }
  }
#pragma unroll
  for (int ii = 0; ii < 2; ++ii)
#pragma unroll
    for (int s = 0; s < SW; ++s)
#pragma unroll
      for (int cc = 0; cc < 3; ++cc)
        out[((pn * L + i0 + ii) * SW + s) * 768 + t + 256 * cc] = acc[ii][s][cc];
}

// ---------------------------------------------------------------------------
// Generic middle conv on the (pn, 128, 9, CIN) strip. Honest 3x3 with borders.
// ---------------------------------------------------------------------------
template <int CIN, int COUT>
__global__ __launch_bounds__(256) void conv_mid_kernel(
    const float* __restrict__ in, const float* __restrict__ w,
    const float* __restrict__ bias, float* __restrict__ out)
{
  const int t  = threadIdx.x;
  const int co = blockIdx.z * 256 + t;
  const int i0 = blockIdx.x * 2;
  const int pn = blockIdx.y;
  const int p  = pn >> 2;

  float acc[2][SW];
#pragma unroll
  for (int ii = 0; ii < 2; ++ii)
#pragma unroll
    for (int s = 0; s < SW; ++s) acc[ii][s] = p ? 0.f : bias[co];

  for (int c = 0; c < CIN; ++c) {
    float iv[4][SW];
#pragma unroll
    for (int r = 0; r < 4; ++r) {
      int row = i0 - 1 + r;
      bool ok = (row >= 0 && row < L);
#pragma unroll
      for (int s = 0; s < SW; ++s)
        iv[r][s] = ok ? in[((pn * L + row) * SW + s) * CIN + c] : 0.f;
    }
#pragma unroll
    for (int di = 0; di < 3; ++di) {
#pragma unroll
      for (int dj = 0; dj < 3; ++dj) {
        const int a = p ? (dj * 3 + di) : (di * 3 + dj);
        const float wv = w[(a * CIN + c) * COUT + co];
#pragma unroll
        for (int ii = 0; ii < 2; ++ii) {
#pragma unroll
          for (int s = 0; s < SW; ++s) {
            const int sc = s + dj - 1;
            if (sc >= 0 && sc < SW) acc[ii][s] += wv * iv[ii + di][sc];
          }
        }
      }
    }
  }
#pragma unroll
  for (int ii = 0; ii < 2; ++ii)
#pragma unroll
    for (int s = 0; s < SW; ++s)
      out[((pn * L + i0 + ii) * SW + s) * COUT + co] = acc[ii][s];
}

// ---------------------------------------------------------------------------
// conv3: 256 -> 1. One block per (pn, i); threads = channels; reduce in block.
// ---------------------------------------------------------------------------
__global__ __launch_bounds__(256) void conv3_kernel(
    const float* __restrict__ in, const float* __restrict__ w,
    const float* __restrict__ b3, float* __restrict__ S)
{
  const int c  = threadIdx.x;  // 256 channels
  const int i  = blockIdx.x;
  const int pn = blockIdx.y;
  const int p  = pn >> 2;

  float part[SW];
#pragma unroll
  for (int s = 0; s < SW; ++s) part[s] = 0.f;

#pragma unroll
  for (int di = 0; di < 3; ++di) {
    const int row = i + di - 1;
    if (row < 0 || row >= L) continue;
    float iv[SW];
#pragma unroll
    for (int s = 0; s < SW; ++s)
      iv[s] = in[((pn * L + row) * SW + s) * 256 + c];
#pragma unroll
    for (int dj = 0; dj < 3; ++dj) {
      const int a = p ? (dj * 3 + di) : (di * 3 + dj);
      const float wv = w[a * 256 + c];
#pragma unroll
      for (int s = 0; s < SW; ++s) {
        const int sc = s + dj - 1;
        if (sc >= 0 && sc < SW) part[s] += wv * iv[sc];
      }
    }
  }
  // wave reduce (64 lanes), then cross-wave via LDS
#pragma unroll
  for (int s = 0; s < SW; ++s)
    for (int off = 32; off; off >>= 1)
      part[s] += __shfl_down(part[s], off, 64);

  __shared__ float red[4][SW];
  const int wave = c >> 6, lane = c & 63;
  if (lane == 0)
#pragma unroll
    for (int s = 0; s < SW; ++s) red[wave][s] = part[s];
  __syncthreads();
  if (c < SW) {
    float v = red[0][c] + red[1][c] + red[2][c] + red[3][c] + (p ? 0.f : b3[0]);
    S[(pn * L + i) * SW + c] = v;
  }
}

// ---------------------------------------------------------------------------
// out[n,i,j] = S[n,i,cls(j)] + S[n,j,cls(i)] where S = passA + passB^T
// ---------------------------------------------------------------------------
__global__ __launch_bounds__(256) void final_kernel(
    const float* __restrict__ S, float* __restrict__ out)
{
  const int idx = blockIdx.x * 256 + threadIdx.x;  // 65536
  const int n = idx >> 14;
  const int i = (idx >> 7) & 127;
  const int j = idx & 127;
  const int ci = (i < 4) ? i : (i > 123 ? i - 119 : 4);
  const int cj = (j < 4) ? j : (j > 123 ? j - 119 : 4);
  const float v = S[((n) * L + i) * SW + cj] + S[((4 + n) * L + i) * SW + cj] +
                  S[((n) * L + j) * SW + ci] + S[((4 + n) * L + j) * SW + ci];
  out[idx] = v;
}

extern "C" void kernel_launch(void* const* d_in, const int* in_sizes, int n_in,
                              void* d_out, int out_size, void* d_ws, size_t ws_size,
                              hipStream_t stream)
{
  const float* batch = (const float*)d_in[0];
  const float* w0 = (const float*)d_in[1];
  const float* b0 = (const float*)d_in[2];
  const float* w1 = (const float*)d_in[3];
  const float* b1 = (const float*)d_in[4];
  const float* w2 = (const float*)d_in[5];
  const float* b2 = (const float*)d_in[6];
  const float* w3 = (const float*)d_in[7];
  const float* b3 = (const float*)d_in[8];

  float* bufA = (float*)d_ws;            // 8*128*9*768 = 7,077,888 floats (28.3 MB)
  float* bufB = bufA + 7077888;          // 8*128*9*512 = 4,718,592 floats (18.9 MB)
  float* S    = bufB;                    // 8*128*9 floats, reuses bufB (h1 dead by then)

  // pass A (pn=0..3) + pass B transposed (pn=4..7), batched together
  conv0_kernel<<<dim3(64, 8), 256, 0, stream>>>(batch, w0, b0, bufA);
  conv_mid_kernel<768, 512><<<dim3(64, 8, 2), 256, 0, stream>>>(bufA, w1, b1, bufB);
  conv_mid_kernel<512, 256><<<dim3(64, 8, 1), 256, 0, stream>>>(bufB, w2, b2, bufA);
  conv3_kernel<<<dim3(L, 8), 256, 0, stream>>>(bufA, w3, b3, S);
  final_kernel<<<dim3(256), 256, 0, stream>>>(S, (float*)d_out);
}

// Round 5
// 2023.378 us; speedup vs baseline: 2.3098x; 2.3098x over previous
//
#include <hip/hip_runtime.h>

#define L 128
#define SW 9

// ---------------------------------------------------------------------------
// Unified im2col GEMM conv over the 9-col strip.
// Tile: M=64 (i-rows) x N=128 (co), BK=32. 256 threads, 8x4 outputs each.
// INBCAST: layer-0 (input = batch, constant along strip; weight half + spatial
//          transpose selected by p = pn>>2).
// CLSIN:   input strip has only cols {0,4,8} distinct (conv0 output) -> map.
// grid: x = iblk(2) + 2*cblk, y = pn(8), z = s_out (9, or 3 reps for conv0)
// ---------------------------------------------------------------------------
template <int CIN, int COUT, int WCIN, bool INBCAST, bool CLSIN>
__global__ __launch_bounds__(256) void conv_gemm(
    const float* __restrict__ in, const float* __restrict__ w,
    const float* __restrict__ bias, float* __restrict__ out)
{
  const int t = threadIdx.x;
  const int iblk = blockIdx.x & 1, cblk = blockIdx.x >> 1;
  const int pn = blockIdx.y, p = pn >> 2, n = pn & 3;
  const int zz = blockIdx.z;
  const int s_out = INBCAST ? (zz == 0 ? 0 : (zz == 1 ? 4 : 8)) : zz;
  const int i0 = iblk * 64;
  const int nbase = cblk * 128;
  const int woff = INBCAST ? p * 768 : 0;

  __shared__ float A[32][68];    // [k][m], pad->68 keeps 16B rows, ~floor banks
  __shared__ float B[32][132];   // [k][n], pad->132

  // valid dj range (strip border clipping); taps enumerated arithmetically
  const int djlo = (s_out == 0) ? 1 : 0;
  const int djhi = (s_out == SW - 1) ? 1 : 2;
  const int ndj = djhi - djlo + 1;
  const int KC = CIN / 32;
  const int total = 3 * ndj * KC;

  // staging coords
  const int sm  = t >> 2;          // A: i-offset 0..63
  const int sk0 = (t & 3) * 8;     // A: k chunk
  const int bk  = t >> 3;          // B: k row 0..31
  const int bn0 = (t & 7) * 16;    // B: col seg

  // compute coords
  const int tm = t >> 5;           // 0..7
  const int tn = t & 31;           // 0..31

  float ar[8], br[16];
  float acc[8][4];
#pragma unroll
  for (int mm = 0; mm < 8; ++mm)
#pragma unroll
    for (int nn = 0; nn < 4; ++nn) acc[mm][nn] = 0.f;

  auto loadG = [&](int it) {
    const int apos = it / KC, kc = it - apos * KC;
    const int di = apos / ndj, dj = djlo + apos % ndj;
    const int c0 = kc * 32;
    // ---- A (im2col activations) ----
    const int irow = i0 + sm + di - 1;
    const bool ok = (irow >= 0) && (irow < L);
    if (ok) {
      const float* ap;
      if (INBCAST) {
        ap = in + (size_t)(irow * 4 + n) * 768 + c0 + sk0;
      } else {
        int s_in = s_out + dj - 1;
        if (CLSIN) s_in = (s_in == 0) ? 0 : (s_in == SW - 1 ? SW - 1 : 4);
        ap = in + ((size_t)(pn * L + irow) * SW + s_in) * CIN + c0 + sk0;
      }
      float4 v0 = *(const float4*)(ap);
      float4 v1 = *(const float4*)(ap + 4);
      ar[0]=v0.x; ar[1]=v0.y; ar[2]=v0.z; ar[3]=v0.w;
      ar[4]=v1.x; ar[5]=v1.y; ar[6]=v1.z; ar[7]=v1.w;
    } else {
#pragma unroll
      for (int j = 0; j < 8; ++j) ar[j] = 0.f;
    }
    // ---- B (weights) ----
    const int a_w = p ? (dj * 3 + di) : (di * 3 + dj);
    const float* bp = w + (size_t)(a_w * WCIN + woff + c0 + bk) * COUT + nbase + bn0;
#pragma unroll
    for (int q = 0; q < 4; ++q) {
      float4 v = *(const float4*)(bp + q * 4);
      br[q*4+0]=v.x; br[q*4+1]=v.y; br[q*4+2]=v.z; br[q*4+3]=v.w;
    }
  };

  auto storeLDS = [&]() {
#pragma unroll
    for (int j = 0; j < 8; ++j) A[sk0 + j][sm] = ar[j];
#pragma unroll
    for (int q = 0; q < 4; ++q)
      *(float4*)&B[bk][bn0 + q * 4] =
          make_float4(br[q*4], br[q*4+1], br[q*4+2], br[q*4+3]);
  };

  loadG(0);
  for (int it = 0; it < total; ++it) {
    __syncthreads();
    storeLDS();
    __syncthreads();
    if (it + 1 < total) loadG(it + 1);   // prefetch overlaps compute
#pragma unroll 8
    for (int k = 0; k < 32; ++k) {
      float4 a0 = *(const float4*)&A[k][tm * 8];
      float4 a1 = *(const float4*)&A[k][tm * 8 + 4];
      float af[8] = {a0.x, a0.y, a0.z, a0.w, a1.x, a1.y, a1.z, a1.w};
      float2 b0 = *(const float2*)&B[k][tn * 2];
      float2 b1 = *(const float2*)&B[k][tn * 2 + 64];
#pragma unroll
      for (int mm = 0; mm < 8; ++mm) {
        acc[mm][0] += af[mm] * b0.x;
        acc[mm][1] += af[mm] * b0.y;
        acc[mm][2] += af[mm] * b1.x;
        acc[mm][3] += af[mm] * b1.y;
      }
    }
  }

  // epilogue
#pragma unroll
  for (int mm = 0; mm < 8; ++mm) {
    const int i = i0 + tm * 8 + mm;
    const size_t obase = ((size_t)(pn * L + i) * SW + s_out) * COUT + nbase;
#pragma unroll
    for (int j = 0; j < 2; ++j) {
      const int c = tn * 2 + 64 * j;
      float2 v;
      v.x = acc[mm][j * 2 + 0];
      v.y = acc[mm][j * 2 + 1];
      if (p == 0) { v.x += bias[nbase + c]; v.y += bias[nbase + c + 1]; }
      *(float2*)&out[obase + c] = v;
    }
  }
}

// ---------------------------------------------------------------------------
// conv3: 256 -> 1. One block per (pn, i); threads = channels; reduce in block.
// ---------------------------------------------------------------------------
__global__ __launch_bounds__(256) void conv3_kernel(
    const float* __restrict__ in, const float* __restrict__ w,
    const float* __restrict__ b3, float* __restrict__ S)
{
  const int c  = threadIdx.x;
  const int i  = blockIdx.x;
  const int pn = blockIdx.y;
  const int p  = pn >> 2;

  float part[SW];
#pragma unroll
  for (int s = 0; s < SW; ++s) part[s] = 0.f;

#pragma unroll
  for (int di = 0; di < 3; ++di) {
    const int row = i + di - 1;
    if (row < 0 || row >= L) continue;
    float iv[SW];
#pragma unroll
    for (int s = 0; s < SW; ++s)
      iv[s] = in[((pn * L + row) * SW + s) * 256 + c];
#pragma unroll
    for (int dj = 0; dj < 3; ++dj) {
      const int a = p ? (dj * 3 + di) : (di * 3 + dj);
      const float wv = w[a * 256 + c];
#pragma unroll
      for (int s = 0; s < SW; ++s) {
        const int sc = s + dj - 1;
        if (sc >= 0 && sc < SW) part[s] += wv * iv[sc];
      }
    }
  }
#pragma unroll
  for (int s = 0; s < SW; ++s)
    for (int off = 32; off; off >>= 1)
      part[s] += __shfl_down(part[s], off, 64);

  __shared__ float red[4][SW];
  const int wave = c >> 6, lane = c & 63;
  if (lane == 0)
#pragma unroll
    for (int s = 0; s < SW; ++s) red[wave][s] = part[s];
  __syncthreads();
  if (c < SW) {
    float v = red[0][c] + red[1][c] + red[2][c] + red[3][c] + (p ? 0.f : b3[0]);
    S[(pn * L + i) * SW + c] = v;
  }
}

// ---------------------------------------------------------------------------
// out[n,i,j] = S[n,i,cls(j)] + S[n,j,cls(i)] where S = passA + passB^T
// ---------------------------------------------------------------------------
__global__ __launch_bounds__(256) void final_kernel(
    const float* __restrict__ S, float* __restrict__ out)
{
  const int idx = blockIdx.x * 256 + threadIdx.x;
  const int n = idx >> 14;
  const int i = (idx >> 7) & 127;
  const int j = idx & 127;
  const int ci = (i < 4) ? i : (i > 123 ? i - 119 : 4);
  const int cj = (j < 4) ? j : (j > 123 ? j - 119 : 4);
  const float v = S[((n) * L + i) * SW + cj] + S[((4 + n) * L + i) * SW + cj] +
                  S[((n) * L + j) * SW + ci] + S[((4 + n) * L + j) * SW + ci];
  out[idx] = v;
}

extern "C" void kernel_launch(void* const* d_in, const int* in_sizes, int n_in,
                              void* d_out, int out_size, void* d_ws, size_t ws_size,
                              hipStream_t stream)
{
  const float* batch = (const float*)d_in[0];
  const float* w0 = (const float*)d_in[1];
  const float* b0 = (const float*)d_in[2];
  const float* w1 = (const float*)d_in[3];
  const float* b1 = (const float*)d_in[4];
  const float* w2 = (const float*)d_in[5];
  const float* b2 = (const float*)d_in[6];
  const float* w3 = (const float*)d_in[7];
  const float* b3 = (const float*)d_in[8];

  float* bufA = (float*)d_ws;            // 8*128*9*768 floats (28.3 MB)
  float* bufB = bufA + 7077888;          // 8*128*9*512 floats (18.9 MB)
  float* S    = bufB;                    // 8*128*9 floats, reuses bufB

  // conv0: batch -> bufA (cols {0,4,8} only; 1..7 == col4 by construction)
  conv_gemm<768, 768, 1536, true,  false>
      <<<dim3(12, 8, 3), 256, 0, stream>>>(batch, w0, b0, bufA);
  // conv1: bufA (class-mapped reads) -> bufB, all 9 cols
  conv_gemm<768, 512,  768, false, true>
      <<<dim3(8, 8, 9), 256, 0, stream>>>(bufA, w1, b1, bufB);
  // conv2: bufB -> bufA, all 9 cols
  conv_gemm<512, 256,  512, false, false>
      <<<dim3(4, 8, 9), 256, 0, stream>>>(bufB, w2, b2, bufA);
  conv3_kernel<<<dim3(L, 8), 256, 0, stream>>>(bufA, w3, b3, S);
  final_kernel<<<dim3(256), 256, 0, stream>>>(S, (float*)d_out);
}

// Round 9
// 694.609 us; speedup vs baseline: 6.7283x; 2.9130x over previous
//
#include <hip/hip_runtime.h>

#define L 128

typedef __attribute__((ext_vector_type(8))) short short8;
typedef __attribute__((ext_vector_type(4))) float f32x4;

static __device__ __forceinline__ short f2bf(float f) {
  unsigned u = __float_as_uint(f);
  u = u + 0x7fffu + ((u >> 16) & 1u);   // RNE bf16
  return (short)(u >> 16);
}
static __device__ __forceinline__ float bf2f(short s) {
  return __uint_as_float(((unsigned)(unsigned short)s) << 16);
}

// ---------------------------------------------------------------------------
// Tiled transpose fp32[slice][R][C] -> bf16[slice][C][R]
// ---------------------------------------------------------------------------
__global__ __launch_bounds__(256) void transpose_bf16(
    const float* __restrict__ in, short* __restrict__ out, int R, int C)
{
  __shared__ float tile[32][33];
  const int tx = threadIdx.x & 31, ty = threadIdx.x >> 5;
  const size_t slice = (size_t)blockIdx.z * R * C;
  const int c0 = blockIdx.x * 32, r0 = blockIdx.y * 32;
#pragma unroll
  for (int q = 0; q < 4; ++q)
    tile[ty + q * 8][tx] = in[slice + (size_t)(r0 + ty + q * 8) * C + c0 + tx];
  __syncthreads();
#pragma unroll
  for (int q = 0; q < 4; ++q)
    out[slice + (size_t)(c0 + ty + q * 8) * R + r0 + tx] = f2bf(tile[tx][ty + q * 8]);
}

__global__ __launch_bounds__(256) void cvt_bf16(
    const float* __restrict__ in, short* __restrict__ out)
{
  const int idx = (blockIdx.x * 256 + threadIdx.x) * 4;
  float4 v = *(const float4*)(in + idx);
  unsigned lo = (unsigned short)f2bf(v.x) | ((unsigned)(unsigned short)f2bf(v.y) << 16);
  unsigned hi = (unsigned short)f2bf(v.z) | ((unsigned)(unsigned short)f2bf(v.w) << 16);
  *(uint2*)(out + idx) = make_uint2(lo, hi);
}

// ---------------------------------------------------------------------------
// MFMA conv over class-compressed strip.
// MODE 0: conv0 (input = batch_bf, j-independent; weight slice 2a+p)
// MODE 1: conv1 (input 3-class)   MODE 2: conv2 (input 5-class)
// grid: x = mblk(2) + 2*nblk, y = pn(8), z = out-class
// block: 256 thr = 4 waves (2x2), tile 64x64, wave 32x32 (2x2 frags 16x16)
// ---------------------------------------------------------------------------
template <int MODE> __device__ __forceinline__ int s9_of_z(int z) {
  if (MODE == 0) return z * 4;                       // {0,4,8}
  if (MODE == 1) return z < 2 ? z : (z == 2 ? 4 : z + 4);   // {0,1,4,7,8}
  return z < 3 ? z : (z == 3 ? 4 : z + 2);           // {0,1,2,4,6,7,8}
}
template <int MODE> __device__ __forceinline__ int cls_in(int s9) {
  if (MODE == 1) return s9 == 0 ? 0 : (s9 == 8 ? 2 : 1);            // 3-class
  return s9 == 0 ? 0 : s9 == 1 ? 1 : s9 == 7 ? 3 : s9 == 8 ? 4 : 2; // 5-class
}

template <int CIN, int COUT, int NSIN, int NSOUT, int MODE>
__global__ __launch_bounds__(256) void conv_mfma(
    const short* __restrict__ inb, const short* __restrict__ wt,
    const float* __restrict__ bias, short* __restrict__ outb)
{
  const int t = threadIdx.x;
  const int l = t & 63, w = t >> 6;
  const int wm = w >> 1, wn = w & 1;
  const int mblk = blockIdx.x & 1, nblk = blockIdx.x >> 1;
  const int pn = blockIdx.y, p = pn >> 2, n = pn & 3;
  const int z = blockIdx.z;
  const int s9 = s9_of_z<MODE>(z);

  const int lm = l & 15;         // A-row / B-col / D-col lane index
  const int lk = (l >> 4) * 8;   // k offset (8 contiguous bf16)

  const int i_base = mblk * 64 + wm * 32;
  const int colbase = nblk * 64 + wn * 32;

  f32x4 acc00 = {0.f, 0.f, 0.f, 0.f};
  f32x4 acc01 = {0.f, 0.f, 0.f, 0.f};
  f32x4 acc10 = {0.f, 0.f, 0.f, 0.f};
  f32x4 acc11 = {0.f, 0.f, 0.f, 0.f};
  const short8 zero8 = {0, 0, 0, 0, 0, 0, 0, 0};

  const int djlo = (z == 0) ? 1 : 0;
  const int djhi = (z == NSOUT - 1) ? 1 : 2;

  const size_t bcol0 = (size_t)(colbase + lm) * CIN + lk;
  const size_t bcol1 = (size_t)(colbase + 16 + lm) * CIN + lk;

  for (int di = 0; di < 3; ++di) {
    const int row0 = i_base + lm + di - 1;
    const int row1 = row0 + 16;
    const bool ok0 = (row0 >= 0) && (row0 < L);
    const bool ok1 = (row1 >= 0) && (row1 < L);
    for (int dj = djlo; dj <= djhi; ++dj) {
      const int a = p ? dj * 3 + di : di * 3 + dj;
      const short* wb = wt + (size_t)(MODE == 0 ? a * 2 + p : a) * COUT * CIN;
      const short *ab0, *ab1;
      if (MODE == 0) {
        ab0 = ok0 ? inb + (size_t)(row0 * 4 + n) * 768 + lk : inb;
        ab1 = ok1 ? inb + (size_t)(row1 * 4 + n) * 768 + lk : inb;
      } else {
        const int cls = cls_in<MODE>(s9 + dj - 1);
        ab0 = ok0 ? inb + ((size_t)(pn * L + row0) * NSIN + cls) * CIN + lk : inb;
        ab1 = ok1 ? inb + ((size_t)(pn * L + row1) * NSIN + cls) * CIN + lk : inb;
      }
      const short* bp0 = wb + bcol0;
      const short* bp1 = wb + bcol1;
#pragma unroll 2
      for (int c0 = 0; c0 < CIN; c0 += 32) {
        short8 a0 = *(const short8*)(ab0 + c0);
        short8 a1 = *(const short8*)(ab1 + c0);
        short8 b0 = *(const short8*)(bp0 + c0);
        short8 b1 = *(const short8*)(bp1 + c0);
        a0 = ok0 ? a0 : zero8;
        a1 = ok1 ? a1 : zero8;
        acc00 = __builtin_amdgcn_mfma_f32_16x16x32_bf16(a0, b0, acc00, 0, 0, 0);
        acc01 = __builtin_amdgcn_mfma_f32_16x16x32_bf16(a0, b1, acc01, 0, 0, 0);
        acc10 = __builtin_amdgcn_mfma_f32_16x16x32_bf16(a1, b0, acc10, 0, 0, 0);
        acc11 = __builtin_amdgcn_mfma_f32_16x16x32_bf16(a1, b1, acc11, 0, 0, 0);
      }
    }
  }

  // epilogue: D col = lm, row = (l>>4)*4 + r
  const int orow = (l >> 4) * 4;
#pragma unroll
  for (int mf = 0; mf < 2; ++mf) {
#pragma unroll
    for (int nf = 0; nf < 2; ++nf) {
      const f32x4 A = mf == 0 ? (nf == 0 ? acc00 : acc01)
                              : (nf == 0 ? acc10 : acc11);
      const int col = colbase + nf * 16 + lm;
      const float bv = (p == 0) ? bias[col] : 0.f;
#pragma unroll
      for (int r = 0; r < 4; ++r) {
        const int i = i_base + mf * 16 + orow + r;
        outb[((size_t)(pn * L + i) * NSOUT + z) * COUT + col] = f2bf(A[r] + bv);
      }
    }
  }
}

// ---------------------------------------------------------------------------
// conv3: 256 -> 1 on 7-class bf16 strip; writes full 9-col S (fp32).
// ---------------------------------------------------------------------------
__global__ __launch_bounds__(256) void conv3_kernel(
    const short* __restrict__ in, const float* __restrict__ w,
    const float* __restrict__ b3, float* __restrict__ S)
{
  const int c = threadIdx.x;
  const int i = blockIdx.x;
  const int pn = blockIdx.y;
  const int p = pn >> 2;

  float part[9];
#pragma unroll
  for (int s = 0; s < 9; ++s) part[s] = 0.f;

#pragma unroll
  for (int di = 0; di < 3; ++di) {
    const int row = i + di - 1;
    if (row < 0 || row >= L) continue;
    float iv[7];
#pragma unroll
    for (int cc = 0; cc < 7; ++cc)
      iv[cc] = bf2f(in[((size_t)(pn * L + row) * 7 + cc) * 256 + c]);
#pragma unroll
    for (int dj = 0; dj < 3; ++dj) {
      const int a = p ? dj * 3 + di : di * 3 + dj;
      const float wv = w[a * 256 + c];
#pragma unroll
      for (int s = 0; s < 9; ++s) {
        const int sc = s + dj - 1;
        if (sc < 0 || sc > 8) continue;
        const int cc = sc <= 2 ? sc : (sc >= 6 ? sc - 2 : 3);
        part[s] += wv * iv[cc];
      }
    }
  }
#pragma unroll
  for (int s = 0; s < 9; ++s)
    for (int off = 32; off; off >>= 1)
      part[s] += __shfl_down(part[s], off, 64);

  __shared__ float red[4][9];
  const int wave = c >> 6, lane = c & 63;
  if (lane == 0)
#pragma unroll
    for (int s = 0; s < 9; ++s) red[wave][s] = part[s];
  __syncthreads();
  if (c < 9) {
    float v = red[0][c] + red[1][c] + red[2][c] + red[3][c] + (p ? 0.f : b3[0]);
    S[((size_t)pn * L + i) * 9 + c] = v;
  }
}

// ---------------------------------------------------------------------------
// out[n,i,j] = (SA+SB)[i,cls9(j)] + (SA+SB)[j,cls9(i)]
// ---------------------------------------------------------------------------
__global__ __launch_bounds__(256) void final_kernel(
    const float* __restrict__ S, float* __restrict__ out)
{
  const int idx = blockIdx.x * 256 + threadIdx.x;
  const int n = idx >> 14;
  const int i = (idx >> 7) & 127;
  const int j = idx & 127;
  const int ci = (i < 4) ? i : (i > 123 ? i - 119 : 4);
  const int cj = (j < 4) ? j : (j > 123 ? j - 119 : 4);
  const float v = S[((n)*L + i) * 9 + cj] + S[((4 + n) * L + i) * 9 + cj] +
                  S[((n)*L + j) * 9 + ci] + S[((4 + n) * L + j) * 9 + ci];
  out[idx] = v;
}

extern "C" void kernel_launch(void* const* d_in, const int* in_sizes, int n_in,
                              void* d_out, int out_size, void* d_ws, size_t ws_size,
                              hipStream_t stream)
{
  const float* batch = (const float*)d_in[0];
  const float* w0 = (const float*)d_in[1];
  const float* b0 = (const float*)d_in[2];
  const float* w1 = (const float*)d_in[3];
  const float* b1 = (const float*)d_in[4];
  const float* w2 = (const float*)d_in[5];
  const float* b2 = (const float*)d_in[6];
  const float* w3 = (const float*)d_in[7];
  const float* b3 = (const float*)d_in[8];

  // ws layout (bf16 shorts unless noted), total ~45.1 MB
  short* wt0 = (short*)d_ws;                           // [2a+p][co 768][ci 768]
  short* wt1 = wt0 + (size_t)18 * 768 * 768;           // [a][co 512][ci 768]
  short* wt2 = wt1 + (size_t)9 * 512 * 768;            // [a][co 256][ci 512]
  short* bbf = wt2 + (size_t)9 * 256 * 512;            // batch bf16 [i][n][768]
  short* bufA = bbf + 393216;                          // [pn][i][3][768]
  short* bufB = bufA + (size_t)8 * L * 3 * 768;        // [pn][i][5][512]
  short* bufC = bufB + (size_t)8 * L * 5 * 512;        // [pn][i][7][256]
  float* S    = (float*)(bufC + (size_t)8 * L * 7 * 256);  // [pn][i][9] fp32

  // prep: weight transposes to [slice][co][ci] bf16 + batch convert
  transpose_bf16<<<dim3(24, 24, 18), 256, 0, stream>>>(w0, wt0, 768, 768);
  transpose_bf16<<<dim3(16, 24, 9), 256, 0, stream>>>(w1, wt1, 768, 512);
  transpose_bf16<<<dim3(8, 16, 9), 256, 0, stream>>>(w2, wt2, 512, 256);
  cvt_bf16<<<dim3(384), 256, 0, stream>>>(batch, bbf);

  conv_mfma<768, 768, 1, 3, 0><<<dim3(24, 8, 3), 256, 0, stream>>>(bbf, wt0, b0, bufA);
  conv_mfma<768, 512, 3, 5, 1><<<dim3(16, 8, 5), 256, 0, stream>>>(bufA, wt1, b1, bufB);
  conv_mfma<512, 256, 5, 7, 2><<<dim3(8, 8, 7), 256, 0, stream>>>(bufB, wt2, b2, bufC);
  conv3_kernel<<<dim3(L, 8), 256, 0, stream>>>(bufC, w3, b3, S);
  final_kernel<<<dim3(256), 256, 0, stream>>>(S, (float*)d_out);
}

// Round 12
// 501.331 us; speedup vs baseline: 9.3222x; 1.3855x over previous
//
#include <hip/hip_runtime.h>

#define L 128

typedef __attribute__((ext_vector_type(8))) short short8;
typedef __attribute__((ext_vector_type(4))) float f32x4;

static __device__ __forceinline__ short f2bf(float f) {
  unsigned u = __float_as_uint(f);
  u = u + 0x7fffu + ((u >> 16) & 1u);   // RNE bf16
  return (short)(u >> 16);
}
static __device__ __forceinline__ float bf2f(short s) {
  return __uint_as_float(((unsigned)(unsigned short)s) << 16);
}

// ---------------------------------------------------------------------------
// Tiled transpose fp32[slice][R][C] -> bf16[slice][C][R]
// ---------------------------------------------------------------------------
__global__ __launch_bounds__(256) void transpose_bf16(
    const float* __restrict__ in, short* __restrict__ out, int R, int C)
{
  __shared__ float tile[32][33];
  const int tx = threadIdx.x & 31, ty = threadIdx.x >> 5;
  const size_t slice = (size_t)blockIdx.z * R * C;
  const int c0 = blockIdx.x * 32, r0 = blockIdx.y * 32;
#pragma unroll
  for (int q = 0; q < 4; ++q)
    tile[ty + q * 8][tx] = in[slice + (size_t)(r0 + ty + q * 8) * C + c0 + tx];
  __syncthreads();
#pragma unroll
  for (int q = 0; q < 4; ++q)
    out[slice + (size_t)(c0 + ty + q * 8) * R + r0 + tx] = f2bf(tile[tx][ty + q * 8]);
}

__global__ __launch_bounds__(256) void cvt_bf16(
    const float* __restrict__ in, short* __restrict__ out)
{
  const int idx = (blockIdx.x * 256 + threadIdx.x) * 4;
  float4 v = *(const float4*)(in + idx);
  unsigned lo = (unsigned short)f2bf(v.x) | ((unsigned)(unsigned short)f2bf(v.y) << 16);
  unsigned hi = (unsigned short)f2bf(v.z) | ((unsigned)(unsigned short)f2bf(v.w) << 16);
  *(uint2*)(out + idx) = make_uint2(lo, hi);
}

// ---------------------------------------------------------------------------
// MFMA conv over class-compressed strip, 4-way K-split across waves.
// MODE 0: conv0 (input = batch_bf, j-independent; weight slice 2a+p)
// MODE 1: conv1 (input 3-class)   MODE 2: conv2 (input 5-class)
// grid: x = mt(4) + 4*nt(COUT/64), y = pn(8), z = out-class
// block: 256 thr = 4 waves; block tile 32x64; wave w takes kc % 4 == w chunks
// of every tap; LDS cross-wave reduce; wave 0 epilogue.
// ---------------------------------------------------------------------------
template <int MODE> __device__ __forceinline__ int s9_of_z(int z) {
  if (MODE == 0) return z * 4;                       // {0,4,8}
  if (MODE == 1) return z < 2 ? z : (z == 2 ? 4 : z + 4);   // {0,1,4,7,8}
  return z < 3 ? z : (z == 3 ? 4 : z + 2);           // {0,1,2,4,6,7,8}
}
template <int MODE> __device__ __forceinline__ int cls_in(int s9) {
  if (MODE == 1) return s9 == 0 ? 0 : (s9 == 8 ? 2 : 1);            // 3-class
  return s9 == 0 ? 0 : s9 == 1 ? 1 : s9 == 7 ? 3 : s9 == 8 ? 4 : 2; // 5-class
}

template <int CIN, int COUT, int NSIN, int NSOUT, int MODE>
__global__ __launch_bounds__(256) void conv_mfma(
    const short* __restrict__ inb, const short* __restrict__ wt,
    const float* __restrict__ bias, short* __restrict__ outb)
{
  const int t = threadIdx.x;
  const int l = t & 63, w = t >> 6;          // w = K-split wave id
  const int mt = blockIdx.x & 3;             // 128/32 m-tiles
  const int nt = blockIdx.x >> 2;            // COUT/64 n-tiles
  const int pn = blockIdx.y, p = pn >> 2, n = pn & 3;
  const int z = blockIdx.z;
  const int s9 = s9_of_z<MODE>(z);

  const int lm = l & 15;         // A-row / B-col / D-col lane index
  const int lk = (l >> 4) * 8;   // k offset (8 contiguous bf16)

  const int i_base = mt * 32;
  const int colbase = nt * 64;

  __shared__ float red[3][8][64][4];   // 24 KB: [wave-1][frag][lane][4]

  f32x4 acc[2][4];
#pragma unroll
  for (int mf = 0; mf < 2; ++mf)
#pragma unroll
    for (int nf = 0; nf < 4; ++nf) acc[mf][nf] = (f32x4){0.f, 0.f, 0.f, 0.f};
  const short8 zero8 = {0, 0, 0, 0, 0, 0, 0, 0};

  const int djlo = (z == 0) ? 1 : 0;
  const int djhi = (z == NSOUT - 1) ? 1 : 2;
  constexpr int KC = CIN / 32;   // 32-wide k-chunks (divisible by 4)

  for (int di = 0; di < 3; ++di) {
    const int row0 = i_base + lm + di - 1;
    const int row1 = row0 + 16;
    const bool ok0 = (row0 >= 0) && (row0 < L);
    const bool ok1 = (row1 >= 0) && (row1 < L);
    for (int dj = djlo; dj <= djhi; ++dj) {
      const int a = p ? dj * 3 + di : di * 3 + dj;
      const short* wb = wt + (size_t)(MODE == 0 ? a * 2 + p : a) * COUT * CIN;
      const short *ab0, *ab1;
      if (MODE == 0) {
        ab0 = ok0 ? inb + (size_t)(row0 * 4 + n) * 768 + lk : inb;
        ab1 = ok1 ? inb + (size_t)(row1 * 4 + n) * 768 + lk : inb;
      } else {
        const int cls = cls_in<MODE>(s9 + dj - 1);
        ab0 = ok0 ? inb + ((size_t)(pn * L + row0) * NSIN + cls) * CIN + lk : inb;
        ab1 = ok1 ? inb + ((size_t)(pn * L + row1) * NSIN + cls) * CIN + lk : inb;
      }
      const short* bp0 = wb + (size_t)(colbase + 0  + lm) * CIN + lk;
      const short* bp1 = wb + (size_t)(colbase + 16 + lm) * CIN + lk;
      const short* bp2 = wb + (size_t)(colbase + 32 + lm) * CIN + lk;
      const short* bp3 = wb + (size_t)(colbase + 48 + lm) * CIN + lk;
#pragma unroll 2
      for (int kc = w; kc < KC; kc += 4) {
        const int c0 = kc * 32;
        short8 a0 = *(const short8*)(ab0 + c0);
        short8 a1 = *(const short8*)(ab1 + c0);
        short8 b0 = *(const short8*)(bp0 + c0);
        short8 b1 = *(const short8*)(bp1 + c0);
        short8 b2 = *(const short8*)(bp2 + c0);
        short8 b3 = *(const short8*)(bp3 + c0);
        a0 = ok0 ? a0 : zero8;
        a1 = ok1 ? a1 : zero8;
        acc[0][0] = __builtin_amdgcn_mfma_f32_16x16x32_bf16(a0, b0, acc[0][0], 0, 0, 0);
        acc[0][1] = __builtin_amdgcn_mfma_f32_16x16x32_bf16(a0, b1, acc[0][1], 0, 0, 0);
        acc[0][2] = __builtin_amdgcn_mfma_f32_16x16x32_bf16(a0, b2, acc[0][2], 0, 0, 0);
        acc[0][3] = __builtin_amdgcn_mfma_f32_16x16x32_bf16(a0, b3, acc[0][3], 0, 0, 0);
        acc[1][0] = __builtin_amdgcn_mfma_f32_16x16x32_bf16(a1, b0, acc[1][0], 0, 0, 0);
        acc[1][1] = __builtin_amdgcn_mfma_f32_16x16x32_bf16(a1, b1, acc[1][1], 0, 0, 0);
        acc[1][2] = __builtin_amdgcn_mfma_f32_16x16x32_bf16(a1, b2, acc[1][2], 0, 0, 0);
        acc[1][3] = __builtin_amdgcn_mfma_f32_16x16x32_bf16(a1, b3, acc[1][3], 0, 0, 0);
      }
    }
  }

  // cross-wave K-split reduction (waves 1..3 -> LDS, wave 0 sums)
  if (w) {
#pragma unroll
    for (int mf = 0; mf < 2; ++mf)
#pragma unroll
      for (int nf = 0; nf < 4; ++nf)
        *(f32x4*)&red[w - 1][mf * 4 + nf][l][0] = acc[mf][nf];
  }
  __syncthreads();
  if (w == 0) {
#pragma unroll
    for (int mf = 0; mf < 2; ++mf)
#pragma unroll
      for (int nf = 0; nf < 4; ++nf) {
#pragma unroll
        for (int ww = 0; ww < 3; ++ww) {
          f32x4 v = *(const f32x4*)&red[ww][mf * 4 + nf][l][0];
          acc[mf][nf] += v;
        }
      }
    // epilogue: D col = lm, row = (l>>4)*4 + r
    const int orow = (l >> 4) * 4;
#pragma unroll
    for (int mf = 0; mf < 2; ++mf) {
#pragma unroll
      for (int nf = 0; nf < 4; ++nf) {
        const int col = colbase + nf * 16 + lm;
        const float bv = (p == 0) ? bias[col] : 0.f;
#pragma unroll
        for (int r = 0; r < 4; ++r) {
          const int i = i_base + mf * 16 + orow + r;
          outb[((size_t)(pn * L + i) * NSOUT + z) * COUT + col] =
              f2bf(acc[mf][nf][r] + bv);
        }
      }
    }
  }
}

// ---------------------------------------------------------------------------
// conv3: 256 -> 1 on 7-class bf16 strip; writes full 9-col S (fp32).
// ---------------------------------------------------------------------------
__global__ __launch_bounds__(256) void conv3_kernel(
    const short* __restrict__ in, const float* __restrict__ w,
    const float* __restrict__ b3, float* __restrict__ S)
{
  const int c = threadIdx.x;
  const int i = blockIdx.x;
  const int pn = blockIdx.y;
  const int p = pn >> 2;

  float part[9];
#pragma unroll
  for (int s = 0; s < 9; ++s) part[s] = 0.f;

#pragma unroll
  for (int di = 0; di < 3; ++di) {
    const int row = i + di - 1;
    if (row < 0 || row >= L) continue;
    float iv[7];
#pragma unroll
    for (int cc = 0; cc < 7; ++cc)
      iv[cc] = bf2f(in[((size_t)(pn * L + row) * 7 + cc) * 256 + c]);
#pragma unroll
    for (int dj = 0; dj < 3; ++dj) {
      const int a = p ? dj * 3 + di : di * 3 + dj;
      const float wv = w[a * 256 + c];
#pragma unroll
      for (int s = 0; s < 9; ++s) {
        const int sc = s + dj - 1;
        if (sc < 0 || sc > 8) continue;
        const int cc = sc <= 2 ? sc : (sc >= 6 ? sc - 2 : 3);
        part[s] += wv * iv[cc];
      }
    }
  }
#pragma unroll
  for (int s = 0; s < 9; ++s)
    for (int off = 32; off; off >>= 1)
      part[s] += __shfl_down(part[s], off, 64);

  __shared__ float red[4][9];
  const int wave = c >> 6, lane = c & 63;
  if (lane == 0)
#pragma unroll
    for (int s = 0; s < 9; ++s) red[wave][s] = part[s];
  __syncthreads();
  if (c < 9) {
    float v = red[0][c] + red[1][c] + red[2][c] + red[3][c] + (p ? 0.f : b3[0]);
    S[((size_t)pn * L + i) * 9 + c] = v;
  }
}

// ---------------------------------------------------------------------------
// out[n,i,j] = (SA+SB)[i,cls9(j)] + (SA+SB)[j,cls9(i)]
// ---------------------------------------------------------------------------
__global__ __launch_bounds__(256) void final_kernel(
    const float* __restrict__ S, float* __restrict__ out)
{
  const int idx = blockIdx.x * 256 + threadIdx.x;
  const int n = idx >> 14;
  const int i = (idx >> 7) & 127;
  const int j = idx & 127;
  const int ci = (i < 4) ? i : (i > 123 ? i - 119 : 4);
  const int cj = (j < 4) ? j : (j > 123 ? j - 119 : 4);
  const float v = S[((n)*L + i) * 9 + cj] + S[((4 + n) * L + i) * 9 + cj] +
                  S[((n)*L + j) * 9 + ci] + S[((4 + n) * L + j) * 9 + ci];
  out[idx] = v;
}

extern "C" void kernel_launch(void* const* d_in, const int* in_sizes, int n_in,
                              void* d_out, int out_size, void* d_ws, size_t ws_size,
                              hipStream_t stream)
{
  const float* batch = (const float*)d_in[0];
  const float* w0 = (const float*)d_in[1];
  const float* b0 = (const float*)d_in[2];
  const float* w1 = (const float*)d_in[3];
  const float* b1 = (const float*)d_in[4];
  const float* w2 = (const float*)d_in[5];
  const float* b2 = (const float*)d_in[6];
  const float* w3 = (const float*)d_in[7];
  const float* b3 = (const float*)d_in[8];

  // ws layout (bf16 shorts unless noted), total ~45.1 MB
  short* wt0 = (short*)d_ws;                           // [2a+p][co 768][ci 768]
  short* wt1 = wt0 + (size_t)18 * 768 * 768;           // [a][co 512][ci 768]
  short* wt2 = wt1 + (size_t)9 * 512 * 768;            // [a][co 256][ci 512]
  short* bbf = wt2 + (size_t)9 * 256 * 512;            // batch bf16 [i][n][768]
  short* bufA = bbf + 393216;                          // [pn][i][3][768]
  short* bufB = bufA + (size_t)8 * L * 3 * 768;        // [pn][i][5][512]
  short* bufC = bufB + (size_t)8 * L * 5 * 512;        // [pn][i][7][256]
  float* S    = (float*)(bufC + (size_t)8 * L * 7 * 256);  // [pn][i][9] fp32

  // prep: weight transposes to [slice][co][ci] bf16 + batch convert
  transpose_bf16<<<dim3(24, 24, 18), 256, 0, stream>>>(w0, wt0, 768, 768);
  transpose_bf16<<<dim3(16, 24, 9), 256, 0, stream>>>(w1, wt1, 768, 512);
  transpose_bf16<<<dim3(8, 16, 9), 256, 0, stream>>>(w2, wt2, 512, 256);
  cvt_bf16<<<dim3(384), 256, 0, stream>>>(batch, bbf);

  // grid.x = 4 m-tiles * (COUT/64) n-tiles
  conv_mfma<768, 768, 1, 3, 0><<<dim3(48, 8, 3), 256, 0, stream>>>(bbf, wt0, b0, bufA);
  conv_mfma<768, 512, 3, 5, 1><<<dim3(32, 8, 5), 256, 0, stream>>>(bufA, wt1, b1, bufB);
  conv_mfma<512, 256, 5, 7, 2><<<dim3(16, 8, 7), 256, 0, stream>>>(bufB, wt2, b2, bufC);
  conv3_kernel<<<dim3(L, 8), 256, 0, stream>>>(bufC, w3, b3, S);
  final_kernel<<<dim3(256), 256, 0, stream>>>(S, (float*)d_out);
}